// Round 1
// baseline (1347.006 us; speedup 1.0000x reference)
//
#include <hip/hip_runtime.h>
#include <hip/hip_bf16.h>
#include <stdint.h>

// SelfAttention B=4 S=4096 D=1024, fp32 in/out.
// Pipeline:
//   1) split x, Wq/Wk/Wv into bf16 hi/lo pairs (fp32 ~= hi + lo)
//   2) Q,K = split-GEMM (3-pass via K'=3072 region cat [hi|lo|hi]x[hi|hi|lo]),
//      stored as bf16 hi/lo. V = split-GEMM stored transposed bf16 (V_t[b][d][k]).
//   3) per batch: scores = Q K^T / 32 (split GEMM, fp32 out)
//               -> row softmax -> P bf16 -> out = P V_t^T (single-bf16 GEMM)
// ws layout (256MB): Qhi 0, Qlo 32M, Khi 64M, Klo 96M, Vt 128M,
//   Xhi 160M, Xlo 192M (reused as scores fp32 after projections),
//   P 224M (overlaps W-splits which are dead after projections).

typedef __attribute__((ext_vector_type(4))) float f32x4;
typedef __attribute__((ext_vector_type(8))) short s16x8;
typedef __attribute__((ext_vector_type(4))) unsigned short u16x4;
typedef unsigned int u32;
typedef unsigned short u16;

__device__ __forceinline__ u16 f2b(float f) {   // fp32 -> bf16 RNE
  u32 u = __float_as_uint(f);
  u = (u + 0x7FFFu + ((u >> 16) & 1u)) >> 16;
  return (u16)u;
}
__device__ __forceinline__ float b2f(u16 h) {
  return __uint_as_float(((u32)h) << 16);
}

__device__ __forceinline__ void gload_lds16(const void* g, void* l) {
  __builtin_amdgcn_global_load_lds(
      (const __attribute__((address_space(1))) void*)(const void*)g,
      (__attribute__((address_space(3))) void*)(void*)l, 16, 0, 0);
}

// ---------------- fp32 -> bf16 hi/lo split ----------------
__global__ __launch_bounds__(256) void k_split(const float* __restrict__ in,
                                               u16* __restrict__ hi,
                                               u16* __restrict__ lo, int n4) {
  int i = blockIdx.x * 256 + threadIdx.x;
  if (i >= n4) return;
  f32x4 f = ((const f32x4*)in)[i];
  u16x4 h, l;
#pragma unroll
  for (int j = 0; j < 4; ++j) {
    u16 hh = f2b(f[j]);
    h[j] = hh;
    l[j] = f2b(f[j] - b2f(hh));
  }
  ((u16x4*)hi)[i] = h;
  ((u16x4*)lo)[i] = l;
}

// ---------------- NT GEMM, bf16 MFMA, region-mapped K ----------------
// C[M,N] = sum_k A[m,k] * B[n,k]; K-tiles of 64 pick region r = k/Kreg from
// {A0,A1,A2}/{B0,B1,B2}. 128x128 tile, BK=64, 4 waves, 16x16x32 bf16 MFMA.
// MODE 0: bias + split store Chi/Clo bf16 (ldc)
// MODE 4: bias + bf16 hi-only store (ldc)
// MODE 1: bias + transposed bf16 store Vt[(row>>12)<<22 | col<<12 | row&4095]
// MODE 2: fp32 store * scale (ldc)
// MODE 3: fp32 store (ldc)
template <int MODE>
__global__ __launch_bounds__(256, 2)
void k_gemm(const u16* __restrict__ A0, const u16* __restrict__ A1,
            const u16* __restrict__ A2, const u16* __restrict__ B0,
            const u16* __restrict__ B1, const u16* __restrict__ B2,
            int lda, int ldb, int Ktot, int Kreg,
            const float* __restrict__ bias, void* __restrict__ C0,
            void* __restrict__ C1, int ldc, float scale) {
  __shared__ __align__(16) u16 As[128 * 64];
  __shared__ __align__(16) u16 Bs[128 * 64];

  const int tid = threadIdx.x;
  const int lane = tid & 63;
  const int wid = tid >> 6;
  const int wr = wid >> 1;
  const int wc = wid & 1;
  const int m0 = blockIdx.y * 128;
  const int n0 = blockIdx.x * 128;

  const int srow = lane >> 3;        // staging: row within 8-row chunk
  const int scol = (lane & 7) * 8;   // staging: col element

  f32x4 acc[4][4] = {};

  const int nkt = Ktot >> 6;
  for (int kt = 0; kt < nkt; ++kt) {
    const int kglob = kt << 6;
    const int r = kglob / Kreg;
    const int kofs = kglob - r * Kreg;
    const u16* Ar = (r == 0) ? A0 : ((r == 1) ? A1 : A2);
    const u16* Br = (r == 0) ? B0 : ((r == 1) ? B1 : B2);
#pragma unroll
    for (int i = 0; i < 4; ++i) {
      const int chunk = wid * 4 + i;           // 16 chunks of 8 rows
      const int row = chunk * 8 + srow;
      gload_lds16(Ar + (size_t)(m0 + row) * lda + (kofs + scol), &As[chunk * 512]);
      gload_lds16(Br + (size_t)(n0 + row) * ldb + (kofs + scol), &Bs[chunk * 512]);
    }
    __syncthreads();
#pragma unroll
    for (int ks = 0; ks < 2; ++ks) {
      const int kk = ks * 32 + (lane >> 4) * 8;
      s16x8 af[4], bfr[4];
#pragma unroll
      for (int mi = 0; mi < 4; ++mi)
        af[mi] = *(const s16x8*)&As[(wr * 64 + mi * 16 + (lane & 15)) * 64 + kk];
#pragma unroll
      for (int ni = 0; ni < 4; ++ni)
        bfr[ni] = *(const s16x8*)&Bs[(wc * 64 + ni * 16 + (lane & 15)) * 64 + kk];
#pragma unroll
      for (int mi = 0; mi < 4; ++mi)
#pragma unroll
        for (int ni = 0; ni < 4; ++ni)
          acc[mi][ni] = __builtin_amdgcn_mfma_f32_16x16x32_bf16(
              af[mi], bfr[ni], acc[mi][ni], 0, 0, 0);
    }
    __syncthreads();
  }

  // epilogue: C row = m-side (lane>>4)*4+reg, col = n-side lane&15 (verified map)
  const int rsub = (lane >> 4) * 4;
#pragma unroll
  for (int ni = 0; ni < 4; ++ni) {
    const int col = n0 + wc * 64 + ni * 16 + (lane & 15);
    float bia = 0.0f;
    if (MODE == 0 || MODE == 1 || MODE == 4) bia = bias[col];
#pragma unroll
    for (int mi = 0; mi < 4; ++mi) {
#pragma unroll
      for (int rr = 0; rr < 4; ++rr) {
        const int row = m0 + wr * 64 + mi * 16 + rsub + rr;
        float v = acc[mi][ni][rr] + bia;
        if (MODE == 0) {
          u16 h = f2b(v);
          ((u16*)C0)[(size_t)row * ldc + col] = h;
          ((u16*)C1)[(size_t)row * ldc + col] = f2b(v - b2f(h));
        } else if (MODE == 4) {
          ((u16*)C0)[(size_t)row * ldc + col] = f2b(v);
        } else if (MODE == 1) {
          ((u16*)C0)[((size_t)(row >> 12) << 22) + ((size_t)col << 12) +
                     (row & 4095)] = f2b(v);
        } else if (MODE == 2) {
          ((float*)C0)[(size_t)row * ldc + col] = v * scale;
        } else {
          ((float*)C0)[(size_t)row * ldc + col] = v;
        }
      }
    }
  }
}

// ---------------- row softmax: fp32 [4096] -> bf16 P [4096] ----------------
__global__ __launch_bounds__(256) void k_softmax(const float* __restrict__ S,
                                                 u16* __restrict__ P) {
  __shared__ float redm[4], reds[4];
  const int row = blockIdx.x;
  const int tid = threadIdx.x;
  const int lane = tid & 63;
  const int wid = tid >> 6;
  const float* sr = S + (size_t)row * 4096;
  f32x4 v[4];
#pragma unroll
  for (int i = 0; i < 4; ++i) v[i] = ((const f32x4*)sr)[i * 256 + tid];
  float m = -3.0e38f;
#pragma unroll
  for (int i = 0; i < 4; ++i)
#pragma unroll
    for (int j = 0; j < 4; ++j) m = fmaxf(m, v[i][j]);
#pragma unroll
  for (int o = 32; o > 0; o >>= 1) m = fmaxf(m, __shfl_xor(m, o, 64));
  if (lane == 0) redm[wid] = m;
  __syncthreads();
  m = fmaxf(fmaxf(redm[0], redm[1]), fmaxf(redm[2], redm[3]));
  float e[16];
  float s = 0.f;
#pragma unroll
  for (int i = 0; i < 4; ++i)
#pragma unroll
    for (int j = 0; j < 4; ++j) {
      float t = __expf(v[i][j] - m);
      e[i * 4 + j] = t;
      s += t;
    }
#pragma unroll
  for (int o = 32; o > 0; o >>= 1) s += __shfl_xor(s, o, 64);
  if (lane == 0) reds[wid] = s;
  __syncthreads();
  s = reds[0] + reds[1] + reds[2] + reds[3];
  const float inv = 1.0f / s;
#pragma unroll
  for (int i = 0; i < 4; ++i) {
    u16x4 h;
#pragma unroll
    for (int j = 0; j < 4; ++j) h[j] = f2b(e[i * 4 + j] * inv);
    ((u16x4*)P)[(size_t)row * 1024 + i * 256 + tid] = h;
  }
}

extern "C" void kernel_launch(void* const* d_in, const int* in_sizes, int n_in,
                              void* d_out, int out_size, void* d_ws,
                              size_t ws_size, hipStream_t stream) {
  const float* x = (const float*)d_in[0];
  const float* Wq = (const float*)d_in[1];
  const float* bq = (const float*)d_in[2];
  const float* Wk = (const float*)d_in[3];
  const float* bk = (const float*)d_in[4];
  const float* Wv = (const float*)d_in[5];
  const float* bv = (const float*)d_in[6];
  float* out = (float*)d_out;
  char* ws = (char*)d_ws;

  const size_t MB = 1ull << 20;
  const bool split_qk = ws_size >= 256 * MB;

  u16 *Qhi, *Qlo = nullptr, *Khi, *Klo = nullptr, *Vt, *Xhi, *Xlo, *P;
  float* Sc;
  u16* Wsp;
  if (split_qk) {
    Qhi = (u16*)(ws + 0 * MB);
    Qlo = (u16*)(ws + 32 * MB);
    Khi = (u16*)(ws + 64 * MB);
    Klo = (u16*)(ws + 96 * MB);
    Vt = (u16*)(ws + 128 * MB);
    Xhi = (u16*)(ws + 160 * MB);
    Xlo = (u16*)(ws + 192 * MB);
    Sc = (float*)(ws + 160 * MB);   // reuses X region after projections
    P = (u16*)(ws + 224 * MB);
    Wsp = (u16*)(ws + 224 * MB);    // dead before P is first written
  } else {
    Qhi = (u16*)(ws + 0 * MB);
    Khi = (u16*)(ws + 32 * MB);
    Vt = (u16*)(ws + 64 * MB);
    Xhi = (u16*)(ws + 96 * MB);
    Xlo = (u16*)(ws + 128 * MB);
    Sc = (float*)(ws + 96 * MB);
    P = (u16*)(ws + 160 * MB);
    Wsp = (u16*)(ws + 160 * MB);
  }
  u16* Wqh = Wsp + 0 * 1048576;
  u16* Wql = Wsp + 1 * 1048576;
  u16* Wkh = Wsp + 2 * 1048576;
  u16* Wkl = Wsp + 3 * 1048576;
  u16* Wvh = Wsp + 4 * 1048576;
  u16* Wvl = Wsp + 5 * 1048576;

  // splits
  k_split<<<16384, 256, 0, stream>>>(x, Xhi, Xlo, 4194304);
  k_split<<<1024, 256, 0, stream>>>(Wq, Wqh, Wql, 262144);
  k_split<<<1024, 256, 0, stream>>>(Wk, Wkh, Wkl, 262144);
  k_split<<<1024, 256, 0, stream>>>(Wv, Wvh, Wvl, 262144);

  dim3 blk(256);
  dim3 gproj(8, 128);  // N=1024, M=16384
  if (split_qk) {
    k_gemm<0><<<gproj, blk, 0, stream>>>(Xhi, Xlo, Xhi, Wqh, Wqh, Wql, 1024,
                                         1024, 3072, 1024, bq, Qhi, Qlo, 1024,
                                         1.f);
    k_gemm<0><<<gproj, blk, 0, stream>>>(Xhi, Xlo, Xhi, Wkh, Wkh, Wkl, 1024,
                                         1024, 3072, 1024, bk, Khi, Klo, 1024,
                                         1.f);
  } else {
    k_gemm<4><<<gproj, blk, 0, stream>>>(Xhi, Xlo, Xhi, Wqh, Wqh, Wql, 1024,
                                         1024, 3072, 1024, bq, Qhi, nullptr,
                                         1024, 1.f);
    k_gemm<4><<<gproj, blk, 0, stream>>>(Xhi, Xlo, Xhi, Wkh, Wkh, Wkl, 1024,
                                         1024, 3072, 1024, bk, Khi, nullptr,
                                         1024, 1.f);
  }
  k_gemm<1><<<gproj, blk, 0, stream>>>(Xhi, Xlo, Xhi, Wvh, Wvh, Wvl, 1024, 1024,
                                       3072, 1024, bv, Vt, nullptr, 0, 1.f);

  const float scale = 0.03125f;  // 1/sqrt(1024)
  for (int b = 0; b < 4; ++b) {
    const size_t qoff = (size_t)b * 4096 * 1024;
    dim3 gs(32, 32);
    if (split_qk) {
      k_gemm<2><<<gs, blk, 0, stream>>>(Qhi + qoff, Qlo + qoff, Qhi + qoff,
                                        Khi + qoff, Khi + qoff, Klo + qoff,
                                        1024, 1024, 3072, 1024, nullptr, Sc,
                                        nullptr, 4096, scale);
    } else {
      k_gemm<2><<<gs, blk, 0, stream>>>(Qhi + qoff, Qhi + qoff, Qhi + qoff,
                                        Khi + qoff, Khi + qoff, Khi + qoff,
                                        1024, 1024, 1024, 1024, nullptr, Sc,
                                        nullptr, 4096, scale);
    }
    k_softmax<<<4096, 256, 0, stream>>>(Sc, P);
    dim3 gpv(8, 32);  // N=1024, M=4096
    const u16* Vb = Vt + ((size_t)b << 22);
    k_gemm<3><<<gpv, blk, 0, stream>>>(P, P, P, Vb, Vb, Vb, 4096, 4096, 4096,
                                       4096, nullptr, out + qoff, nullptr, 1024,
                                       1.f);
  }
}

// Round 3
// 789.073 us; speedup vs baseline: 1.7071x; 1.7071x over previous
//
#include <hip/hip_runtime.h>
#include <hip/hip_bf16.h>
#include <stdint.h>

// SelfAttention B=4 S=4096 D=1024, fp32 in/out. All-single-bf16 pipeline:
//   1) convert x, Wq/Wk/Wv to bf16
//   2) Q,K = x@W^T + b (bf16 MFMA GEMM, bf16 out); V stored transposed
//      Vt[b][d][s] for NT PV
//   3) per batch: Sc = Q K^T / 32 (fp32 out) -> row softmax -> P bf16
//                 -> out = P Vt^T (fp32 out)
// Error budget: score err sigma ~2.5e-3 damped by sqrt(sum p^2)~0.026 through
// softmax; P/V bf16 rounding dominates at ~1e-3 absmax (round-1 baseline was
// 9.8e-4). Est total ~1.5e-3 < 4.84e-3 threshold.
// ws layout (198MB used): Qb 0, Kb 32M, Vt 64M, Xb 96M(32M),
//   Sc 96M(64M fp32, reuses Xb after projections), P 160M(32M), Wb 192M(6M).

typedef __attribute__((ext_vector_type(4))) float f32x4;
typedef __attribute__((ext_vector_type(8))) short s16x8;
typedef __attribute__((ext_vector_type(4))) unsigned short u16x4;
typedef unsigned int u32;
typedef unsigned short u16;

__device__ __forceinline__ u16 f2b(float f) {   // fp32 -> bf16 RNE
  u32 u = __float_as_uint(f);
  u = (u + 0x7FFFu + ((u >> 16) & 1u)) >> 16;
  return (u16)u;
}

__device__ __forceinline__ void gload_lds16(const void* g, void* l) {
  __builtin_amdgcn_global_load_lds(
      (const __attribute__((address_space(1))) void*)(const void*)g,
      (__attribute__((address_space(3))) void*)(void*)l, 16, 0, 0);
}

// ---------------- fp32 -> bf16 convert ----------------
__global__ __launch_bounds__(256) void k_cvt(const float* __restrict__ in,
                                             u16* __restrict__ out, int n4) {
  int i = blockIdx.x * 256 + threadIdx.x;
  if (i >= n4) return;
  f32x4 f = ((const f32x4*)in)[i];
  u16x4 h;
#pragma unroll
  for (int j = 0; j < 4; ++j) h[j] = f2b(f[j]);
  ((u16x4*)out)[i] = h;
}

// ---------------- NT GEMM, bf16 MFMA ----------------
// C[M,N] = sum_k A[m,k]*B[n,k]. 128x128 tile, BK=64, 4 waves, 16x16x32 MFMA.
// MODE 0: bias + bf16 row-major store (ldc)
// MODE 1: bias + transposed bf16 store Vt[(row>>12)<<22 | col<<12 | row&4095]
// MODE 2: fp32 store * scale (ldc)
// MODE 3: fp32 store (ldc)
template <int MODE>
__global__ __launch_bounds__(256, 2)
void k_gemm(const u16* __restrict__ A, const u16* __restrict__ B, int lda,
            int ldb, int K, const float* __restrict__ bias,
            void* __restrict__ C, int ldc, float scale) {
  __shared__ __align__(16) u16 As[128 * 64];
  __shared__ __align__(16) u16 Bs[128 * 64];

  const int tid = threadIdx.x;
  const int lane = tid & 63;
  const int wid = tid >> 6;
  const int wr = wid >> 1;
  const int wc = wid & 1;
  const int m0 = blockIdx.y * 128;
  const int n0 = blockIdx.x * 128;

  const int srow = lane >> 3;        // staging: row within 8-row chunk
  const int scol = (lane & 7) * 8;   // staging: col element

  f32x4 acc[4][4] = {};

  const int nkt = K >> 6;
  for (int kt = 0; kt < nkt; ++kt) {
    const int kofs = kt << 6;
#pragma unroll
    for (int i = 0; i < 4; ++i) {
      const int chunk = wid * 4 + i;           // 16 chunks of 8 rows
      const int row = chunk * 8 + srow;
      gload_lds16(A + (size_t)(m0 + row) * lda + (kofs + scol), &As[chunk * 512]);
      gload_lds16(B + (size_t)(n0 + row) * ldb + (kofs + scol), &Bs[chunk * 512]);
    }
    __syncthreads();
#pragma unroll
    for (int ks = 0; ks < 2; ++ks) {
      const int kk = ks * 32 + (lane >> 4) * 8;
      s16x8 af[4], bfr[4];
#pragma unroll
      for (int mi = 0; mi < 4; ++mi)
        af[mi] = *(const s16x8*)&As[(wr * 64 + mi * 16 + (lane & 15)) * 64 + kk];
#pragma unroll
      for (int ni = 0; ni < 4; ++ni)
        bfr[ni] = *(const s16x8*)&Bs[(wc * 64 + ni * 16 + (lane & 15)) * 64 + kk];
#pragma unroll
      for (int mi = 0; mi < 4; ++mi)
#pragma unroll
        for (int ni = 0; ni < 4; ++ni)
          acc[mi][ni] = __builtin_amdgcn_mfma_f32_16x16x32_bf16(
              af[mi], bfr[ni], acc[mi][ni], 0, 0, 0);
    }
    __syncthreads();
  }

  // epilogue: C row = m-side (lane>>4)*4+reg, col = n-side lane&15
  const int rsub = (lane >> 4) * 4;
#pragma unroll
  for (int ni = 0; ni < 4; ++ni) {
    const int col = n0 + wc * 64 + ni * 16 + (lane & 15);
    float bia = 0.0f;
    if (MODE == 0 || MODE == 1) bia = bias[col];
#pragma unroll
    for (int mi = 0; mi < 4; ++mi) {
#pragma unroll
      for (int rr = 0; rr < 4; ++rr) {
        const int row = m0 + wr * 64 + mi * 16 + rsub + rr;
        float v = acc[mi][ni][rr] + bia;
        if (MODE == 0) {
          ((u16*)C)[(size_t)row * ldc + col] = f2b(v);
        } else if (MODE == 1) {
          ((u16*)C)[((size_t)(row >> 12) << 22) + ((size_t)col << 12) +
                    (row & 4095)] = f2b(v);
        } else if (MODE == 2) {
          ((float*)C)[(size_t)row * ldc + col] = v * scale;
        } else {
          ((float*)C)[(size_t)row * ldc + col] = v;
        }
      }
    }
  }
}

// ---------------- row softmax: fp32 [4096] -> bf16 P [4096] ----------------
__global__ __launch_bounds__(256) void k_softmax(const float* __restrict__ S,
                                                 u16* __restrict__ P) {
  __shared__ float redm[4], reds[4];
  const int row = blockIdx.x;
  const int tid = threadIdx.x;
  const int lane = tid & 63;
  const int wid = tid >> 6;
  const float* sr = S + (size_t)row * 4096;
  f32x4 v[4];
#pragma unroll
  for (int i = 0; i < 4; ++i) v[i] = ((const f32x4*)sr)[i * 256 + tid];
  float m = -3.0e38f;
#pragma unroll
  for (int i = 0; i < 4; ++i)
#pragma unroll
    for (int j = 0; j < 4; ++j) m = fmaxf(m, v[i][j]);
#pragma unroll
  for (int o = 32; o > 0; o >>= 1) m = fmaxf(m, __shfl_xor(m, o, 64));
  if (lane == 0) redm[wid] = m;
  __syncthreads();
  m = fmaxf(fmaxf(redm[0], redm[1]), fmaxf(redm[2], redm[3]));
  float e[16];
  float s = 0.f;
#pragma unroll
  for (int i = 0; i < 4; ++i)
#pragma unroll
    for (int j = 0; j < 4; ++j) {
      float t = __expf(v[i][j] - m);
      e[i * 4 + j] = t;
      s += t;
    }
#pragma unroll
  for (int o = 32; o > 0; o >>= 1) s += __shfl_xor(s, o, 64);
  if (lane == 0) reds[wid] = s;
  __syncthreads();
  s = reds[0] + reds[1] + reds[2] + reds[3];
  const float inv = 1.0f / s;
#pragma unroll
  for (int i = 0; i < 4; ++i) {
    u16x4 h;
#pragma unroll
    for (int j = 0; j < 4; ++j) h[j] = f2b(e[i * 4 + j] * inv);
    ((u16x4*)P)[(size_t)row * 1024 + i * 256 + tid] = h;
  }
}

extern "C" void kernel_launch(void* const* d_in, const int* in_sizes, int n_in,
                              void* d_out, int out_size, void* d_ws,
                              size_t ws_size, hipStream_t stream) {
  const float* x = (const float*)d_in[0];
  const float* Wq = (const float*)d_in[1];
  const float* bq = (const float*)d_in[2];
  const float* Wk = (const float*)d_in[3];
  const float* bk = (const float*)d_in[4];
  const float* Wv = (const float*)d_in[5];
  const float* bv = (const float*)d_in[6];
  float* out = (float*)d_out;
  char* ws = (char*)d_ws;

  const size_t MB = 1ull << 20;
  u16* Qb = (u16*)(ws + 0 * MB);
  u16* Kb = (u16*)(ws + 32 * MB);
  u16* Vt = (u16*)(ws + 64 * MB);
  u16* Xb = (u16*)(ws + 96 * MB);
  float* Sc = (float*)(ws + 96 * MB);  // reuses Xb region after projections
  u16* P = (u16*)(ws + 160 * MB);
  u16* Wqb = (u16*)(ws + 192 * MB);
  u16* Wkb = Wqb + 1048576;
  u16* Wvb = Wqb + 2097152;

  // converts: x is 16,777,216 floats = 4,194,304 float4 (bug in prev round:
  // only 1/4 was converted -> batches 1-3 read poison).
  k_cvt<<<16384, 256, 0, stream>>>(x, Xb, 4194304);
  k_cvt<<<1024, 256, 0, stream>>>(Wq, Wqb, 262144);
  k_cvt<<<1024, 256, 0, stream>>>(Wk, Wkb, 262144);
  k_cvt<<<1024, 256, 0, stream>>>(Wv, Wvb, 262144);

  dim3 blk(256);
  dim3 gproj(8, 128);  // N=1024, M=16384
  k_gemm<0><<<gproj, blk, 0, stream>>>(Xb, Wqb, 1024, 1024, 1024, bq, Qb, 1024,
                                       1.f);
  k_gemm<0><<<gproj, blk, 0, stream>>>(Xb, Wkb, 1024, 1024, 1024, bk, Kb, 1024,
                                       1.f);
  k_gemm<1><<<gproj, blk, 0, stream>>>(Xb, Wvb, 1024, 1024, 1024, bv, Vt, 0,
                                       1.f);

  const float scale = 0.03125f;  // 1/sqrt(1024)
  for (int b = 0; b < 4; ++b) {
    const size_t qoff = (size_t)b * 4096 * 1024;
    dim3 gs(32, 32);
    k_gemm<2><<<gs, blk, 0, stream>>>(Qb + qoff, Kb + qoff, 1024, 1024, 1024,
                                      nullptr, Sc, 4096, scale);
    k_softmax<<<4096, 256, 0, stream>>>(Sc, P);
    dim3 gpv(8, 32);  // N=1024, M=4096
    const u16* Vb = Vt + ((size_t)b << 22);
    k_gemm<3><<<gpv, blk, 0, stream>>>(P, Vb, 4096, 4096, 4096, nullptr,
                                       out + qoff, 1024, 1.f);
  }
}

// Round 4
// 595.072 us; speedup vs baseline: 2.2636x; 1.3260x over previous
//
#include <hip/hip_runtime.h>
#include <hip/hip_bf16.h>
#include <stdint.h>

// SelfAttention B=4 S=4096 D=1024, fp32 in/out. Single-bf16 pipeline:
//   1) convert x, Wq/Wk/Wv to bf16
//   2) Q,K = x@W^T + b (bf16). Vt = Wv@x^T + bv (row d, col s) -> V^T directly
//      with coalesced stores, all batches in one [1024][16384] buffer.
//   3) scores (all 4 batches, one launch, z-grid) = Q K^T / 32, bf16 out
//   4) in-place row softmax (bf16), all 16384 rows, one launch
//   5) PV (all batches, one launch, z-grid): out = P Vt^T, fp32 out
// GEMM: 128x128 tile, BK=64, 4 waves, 16x16x32 bf16 MFMA, global_load_lds
// width-16 staging, bijective XCD-aware block swizzle.
// ws layout (230MB): Qb 0-32, Kb 32-64, VtAll 64-96, Xb 96-128 (dead after
// projections), Sc/P bf16 96-224 (reuses Xb region), Wb 224-230.

typedef __attribute__((ext_vector_type(4))) float f32x4;
typedef __attribute__((ext_vector_type(8))) short s16x8;
typedef __attribute__((ext_vector_type(4))) unsigned short u16x4;
typedef unsigned int u32;
typedef unsigned short u16;

__device__ __forceinline__ u16 f2b(float f) {   // fp32 -> bf16 RNE
  u32 u = __float_as_uint(f);
  u = (u + 0x7FFFu + ((u >> 16) & 1u)) >> 16;
  return (u16)u;
}
__device__ __forceinline__ float b2f(u16 h) {
  return __uint_as_float(((u32)h) << 16);
}

__device__ __forceinline__ void gload_lds16(const void* g, void* l) {
  __builtin_amdgcn_global_load_lds(
      (const __attribute__((address_space(1))) void*)(const void*)g,
      (__attribute__((address_space(3))) void*)(void*)l, 16, 0, 0);
}

// ---------------- fp32 -> bf16 convert ----------------
__global__ __launch_bounds__(256) void k_cvt(const float* __restrict__ in,
                                             u16* __restrict__ out, int n4) {
  int i = blockIdx.x * 256 + threadIdx.x;
  if (i >= n4) return;
  f32x4 f = ((const f32x4*)in)[i];
  u16x4 h;
#pragma unroll
  for (int j = 0; j < 4; ++j) h[j] = f2b(f[j]);
  ((u16x4*)out)[i] = h;
}

// ---------------- NT GEMM, bf16 MFMA, z-batched, XCD-swizzled ----------------
// C[M,N] = sum_k A[m,k]*B[n,k]. 128x128 tile, BK=64, 4 waves.
// MODE 0: bias[col] + bf16 store   (Q/K projections)
// MODE 1: bias[row] + bf16 store   (V^T projection)
// MODE 2: bf16 store of v*scale    (scores)
// MODE 3: fp32 store               (PV output)
// az/bz: per-z element strides for A,B. czb: per-z BYTE stride for C.
template <int MODE>
__global__ __launch_bounds__(256, 2)
void k_gemm(const u16* __restrict__ A, const u16* __restrict__ B, int lda,
            int ldb, int K, const float* __restrict__ bias,
            void* __restrict__ Cv, int ldc, float scale, size_t az, size_t bz,
            size_t czb) {
  __shared__ __align__(16) u16 As[128 * 64];
  __shared__ __align__(16) u16 Bs[128 * 64];

  A += (size_t)blockIdx.z * az;
  B += (size_t)blockIdx.z * bz;
  char* C = (char*)Cv + (size_t)blockIdx.z * czb;

  // bijective XCD-aware swizzle (consecutive tiles per XCD share A-panel)
  const int gx = gridDim.x;
  const int nwg = gx * gridDim.y;
  const int bid = blockIdx.y * gx + blockIdx.x;
  const int q = nwg >> 3, r = nwg & 7;
  const int xcd = bid & 7, idx = bid >> 3;
  const int tile = (xcd < r ? xcd * (q + 1) : r * (q + 1) + (xcd - r) * q) + idx;
  const int m0 = (tile / gx) * 128;
  const int n0 = (tile % gx) * 128;

  const int tid = threadIdx.x;
  const int lane = tid & 63;
  const int wid = tid >> 6;
  const int wr = wid >> 1;
  const int wc = wid & 1;

  const int srow = lane >> 3;        // staging: row within 8-row chunk
  const int scol = (lane & 7) * 8;   // staging: col element

  f32x4 acc[4][4] = {};

  const int nkt = K >> 6;
  for (int kt = 0; kt < nkt; ++kt) {
    const int kofs = kt << 6;
#pragma unroll
    for (int i = 0; i < 4; ++i) {
      const int chunk = wid * 4 + i;           // 16 chunks of 8 rows
      const int row = chunk * 8 + srow;
      gload_lds16(A + (size_t)(m0 + row) * lda + (kofs + scol), &As[chunk * 512]);
      gload_lds16(B + (size_t)(n0 + row) * ldb + (kofs + scol), &Bs[chunk * 512]);
    }
    __syncthreads();
#pragma unroll
    for (int ks = 0; ks < 2; ++ks) {
      const int kk = ks * 32 + (lane >> 4) * 8;
      s16x8 af[4], bfr[4];
#pragma unroll
      for (int mi = 0; mi < 4; ++mi)
        af[mi] = *(const s16x8*)&As[(wr * 64 + mi * 16 + (lane & 15)) * 64 + kk];
#pragma unroll
      for (int ni = 0; ni < 4; ++ni)
        bfr[ni] = *(const s16x8*)&Bs[(wc * 64 + ni * 16 + (lane & 15)) * 64 + kk];
#pragma unroll
      for (int mi = 0; mi < 4; ++mi)
#pragma unroll
        for (int ni = 0; ni < 4; ++ni)
          acc[mi][ni] = __builtin_amdgcn_mfma_f32_16x16x32_bf16(
              af[mi], bfr[ni], acc[mi][ni], 0, 0, 0);
    }
    __syncthreads();
  }

  // epilogue: C row = m-side (lane>>4)*4+reg, col = n-side lane&15
  const int rsub = (lane >> 4) * 4;
  float brow[4][4];
  if (MODE == 1) {
#pragma unroll
    for (int mi = 0; mi < 4; ++mi)
#pragma unroll
      for (int rr = 0; rr < 4; ++rr)
        brow[mi][rr] = bias[m0 + wr * 64 + mi * 16 + rsub + rr];
  }
#pragma unroll
  for (int ni = 0; ni < 4; ++ni) {
    const int col = n0 + wc * 64 + ni * 16 + (lane & 15);
    float bcol = 0.0f;
    if (MODE == 0) bcol = bias[col];
#pragma unroll
    for (int mi = 0; mi < 4; ++mi) {
#pragma unroll
      for (int rr = 0; rr < 4; ++rr) {
        const int row = m0 + wr * 64 + mi * 16 + rsub + rr;
        float v = acc[mi][ni][rr];
        if (MODE == 0) v += bcol;
        if (MODE == 1) v += brow[mi][rr];
        if (MODE == 0 || MODE == 1) {
          ((u16*)C)[(size_t)row * ldc + col] = f2b(v);
        } else if (MODE == 2) {
          ((u16*)C)[(size_t)row * ldc + col] = f2b(v * scale);
        } else {
          ((float*)C)[(size_t)row * ldc + col] = v;
        }
      }
    }
  }
}

// ------------- in-place row softmax on bf16 [nrows][4096] -------------
__global__ __launch_bounds__(256) void k_softmax(u16* __restrict__ S) {
  __shared__ float redm[4], reds[4];
  const int tid = threadIdx.x;
  const int lane = tid & 63;
  const int wid = tid >> 6;
  u16* sr = S + (size_t)blockIdx.x * 4096;
  s16x8 v[2];
#pragma unroll
  for (int i = 0; i < 2; ++i) v[i] = ((const s16x8*)sr)[i * 256 + tid];
  float f[16];
#pragma unroll
  for (int i = 0; i < 2; ++i)
#pragma unroll
    for (int j = 0; j < 8; ++j) f[i * 8 + j] = b2f((u16)v[i][j]);
  float m = -3.0e38f;
#pragma unroll
  for (int i = 0; i < 16; ++i) m = fmaxf(m, f[i]);
#pragma unroll
  for (int o = 32; o > 0; o >>= 1) m = fmaxf(m, __shfl_xor(m, o, 64));
  if (lane == 0) redm[wid] = m;
  __syncthreads();
  m = fmaxf(fmaxf(redm[0], redm[1]), fmaxf(redm[2], redm[3]));
  float s = 0.f;
#pragma unroll
  for (int i = 0; i < 16; ++i) {
    f[i] = __expf(f[i] - m);
    s += f[i];
  }
#pragma unroll
  for (int o = 32; o > 0; o >>= 1) s += __shfl_xor(s, o, 64);
  if (lane == 0) reds[wid] = s;
  __syncthreads();
  s = reds[0] + reds[1] + reds[2] + reds[3];
  const float inv = 1.0f / s;
#pragma unroll
  for (int i = 0; i < 2; ++i) {
    s16x8 h;
#pragma unroll
    for (int j = 0; j < 8; ++j) h[j] = (short)f2b(f[i * 8 + j] * inv);
    ((s16x8*)sr)[i * 256 + tid] = h;
  }
}

extern "C" void kernel_launch(void* const* d_in, const int* in_sizes, int n_in,
                              void* d_out, int out_size, void* d_ws,
                              size_t ws_size, hipStream_t stream) {
  const float* x = (const float*)d_in[0];
  const float* Wq = (const float*)d_in[1];
  const float* bq = (const float*)d_in[2];
  const float* Wk = (const float*)d_in[3];
  const float* bk = (const float*)d_in[4];
  const float* Wv = (const float*)d_in[5];
  const float* bv = (const float*)d_in[6];
  float* out = (float*)d_out;
  char* ws = (char*)d_ws;

  const size_t MB = 1ull << 20;
  u16* Qb = (u16*)(ws + 0 * MB);      // [4][4096][1024] bf16
  u16* Kb = (u16*)(ws + 32 * MB);     // [4][4096][1024] bf16
  u16* VtAll = (u16*)(ws + 64 * MB);  // [1024][16384] bf16 (V^T, all batches)
  u16* Xb = (u16*)(ws + 96 * MB);     // [16384][1024] bf16, dead after proj
  u16* Sc = (u16*)(ws + 96 * MB);     // [4][4096][4096] bf16, reuses Xb
  u16* Wqb = (u16*)(ws + 224 * MB);
  u16* Wkb = Wqb + 1048576;
  u16* Wvb = Wqb + 2097152;

  // converts (x: 16,777,216 floats = 4,194,304 float4)
  k_cvt<<<16384, 256, 0, stream>>>(x, Xb, 4194304);
  k_cvt<<<1024, 256, 0, stream>>>(Wq, Wqb, 262144);
  k_cvt<<<1024, 256, 0, stream>>>(Wk, Wkb, 262144);
  k_cvt<<<1024, 256, 0, stream>>>(Wv, Wvb, 262144);

  dim3 blk(256);
  // Q,K projections: M=16384, N=1024, K=1024
  k_gemm<0><<<dim3(8, 128, 1), blk, 0, stream>>>(Xb, Wqb, 1024, 1024, 1024, bq,
                                                 Qb, 1024, 1.f, 0, 0, 0);
  k_gemm<0><<<dim3(8, 128, 1), blk, 0, stream>>>(Xb, Wkb, 1024, 1024, 1024, bk,
                                                 Kb, 1024, 1.f, 0, 0, 0);
  // V^T projection: C[d][s_global] = Wv@X^T + bv[d]; M=1024, N=16384, K=1024
  k_gemm<1><<<dim3(128, 8, 1), blk, 0, stream>>>(Wvb, Xb, 1024, 1024, 1024, bv,
                                                 VtAll, 16384, 1.f, 0, 0, 0);
  // scores (all batches): M=N=4096, K=1024, bf16 out * 1/32
  k_gemm<2><<<dim3(32, 32, 4), blk, 0, stream>>>(
      Qb, Kb, 1024, 1024, 1024, nullptr, Sc, 4096, 0.03125f, 4194304, 4194304,
      (size_t)4096 * 4096 * 2);
  // softmax in place over all 16384 rows
  k_softmax<<<16384, 256, 0, stream>>>(Sc);
  // PV (all batches): M=4096, N=1024, K=4096; B = VtAll + z*4096, ldb=16384
  k_gemm<3><<<dim3(8, 32, 4), blk, 0, stream>>>(
      Sc, VtAll, 4096, 16384, 4096, nullptr, out, 1024, 1.f, 16777216, 4096,
      (size_t)4096 * 1024 * 4);
}

// Round 5
// 481.164 us; speedup vs baseline: 2.7995x; 1.2367x over previous
//
#include <hip/hip_runtime.h>
#include <hip/hip_bf16.h>
#include <stdint.h>

// SelfAttention B=4 S=4096 D=1024, fp32 in/out. Single-bf16 pipeline:
//   cvt -> Q,K proj (bf16), Vt = Wv@X^T (bf16, transposed direct)
//   -> scores QK^T/32 (bf16, z-batched) -> in-place softmax -> PV (fp32 out).
// GEMM: 256x256 tile, BK=64, 8 waves (2Mx4N), 4-phase/K-tile 8-phase/iter
// schedule (T3+T4 counted vmcnt), st-XOR LDS swizzle (T2, rule-21 pattern:
// linear gload_lds dest + inverse-swizzled global col + swizzled ds_read),
// setprio around MFMA clusters (T5), bijective XCD swizzle (T1).
// LDS 128 KiB dynamic (2 bufs x (A 256x64 + B 256x64) bf16).

typedef __attribute__((ext_vector_type(4))) float f32x4;
typedef __attribute__((ext_vector_type(8))) short s16x8;
typedef __attribute__((ext_vector_type(4))) unsigned short u16x4;
typedef unsigned int u32;
typedef unsigned short u16;

__device__ __forceinline__ u16 f2b(float f) {   // fp32 -> bf16 RNE
  u32 u = __float_as_uint(f);
  u = (u + 0x7FFFu + ((u >> 16) & 1u)) >> 16;
  return (u16)u;
}
__device__ __forceinline__ float b2f(u16 h) {
  return __uint_as_float(((u32)h) << 16);
}

__device__ __forceinline__ void gload_lds16(const void* g, void* l) {
  __builtin_amdgcn_global_load_lds(
      (const __attribute__((address_space(1))) void*)(const void*)g,
      (__attribute__((address_space(3))) void*)(void*)l, 16, 0, 0);
}

#define BARRIER() asm volatile("s_barrier" ::: "memory")
#define WAITLGKM0() asm volatile("s_waitcnt lgkmcnt(0)" ::: "memory")
#define WAITVM4() asm volatile("s_waitcnt vmcnt(4)" ::: "memory")
#define WAITVM0() asm volatile("s_waitcnt vmcnt(0)" ::: "memory")

// ---------------- fp32 -> bf16 convert ----------------
__global__ __launch_bounds__(256) void k_cvt(const float* __restrict__ in,
                                             u16* __restrict__ out, int n4) {
  int i = blockIdx.x * 256 + threadIdx.x;
  if (i >= n4) return;
  f32x4 f = ((const f32x4*)in)[i];
  u16x4 h;
#pragma unroll
  for (int j = 0; j < 4; ++j) h[j] = f2b(f[j]);
  ((u16x4*)out)[i] = h;
}

// ------------- 256^2 8-phase NT GEMM, bf16 MFMA, z-batched -------------
// C[M,N] = sum_k A[m,k]*B[n,k].
// MODE 0: bias[col] + bf16 store   (Q/K projections)
// MODE 1: bias[row] + bf16 store   (V^T projection)
// MODE 2: bf16 store of v*scale    (scores)
// MODE 3: fp32 store               (PV output)
template <int MODE>
__global__ __launch_bounds__(512)
void k_gemm256(const u16* __restrict__ A, const u16* __restrict__ B, int lda,
               int ldb, int K, const float* __restrict__ bias,
               void* __restrict__ Cv, int ldc, float scale, size_t az,
               size_t bz, size_t czb) {
  extern __shared__ __align__(16) u16 lds[];  // 131072 B

  A += (size_t)blockIdx.z * az;
  B += (size_t)blockIdx.z * bz;
  char* C = (char*)Cv + (size_t)blockIdx.z * czb;

  // bijective XCD-aware swizzle
  const int gx = gridDim.x;
  const int nwg = gx * gridDim.y;
  const int bid = blockIdx.y * gx + blockIdx.x;
  const int q = nwg >> 3, r = nwg & 7;
  const int xcd = bid & 7, idx = bid >> 3;
  const int tile = (xcd < r ? xcd * (q + 1) : r * (q + 1) + (xcd - r) * q) + idx;
  const int m0 = (tile / gx) * 256;
  const int n0 = (tile % gx) * 256;

  const int tid = threadIdx.x;
  const int lane = tid & 63;
  const int wid = tid >> 6;
  const int wm = wid >> 2;  // 0..1 (M half)
  const int wn = wid & 3;   // 0..3 (N quarter)

  // staging: each STAGE = one 128x64 half-tile = 2 gload_lds per thread
  const int srow = lane >> 3;                       // 0..7
  const int gcol = (((lane & 7) ^ srow) << 3);      // inverse-swizzled col
  // ds_read constants
  const int rA = lane & 15;
  const int kq = (lane >> 4) << 3;                  // 0,8,16,24
  const int xr = (lane & 7) << 3;                   // read-side swizzle

// half h of A for K-tile kt into buffer b
#define STAGE_A(h, kt, b)                                                    \
  do {                                                                       \
    _Pragma("unroll") for (int j = 0; j < 2; ++j)                            \
        gload_lds16(A + (size_t)(m0 + (h)*128 + j * 64 + wid * 8 + srow) *   \
                            lda + (kt)*64 + gcol,                            \
                    &lds[(b)*32768 + (h)*8192 + j * 4096 + wid * 512]);      \
  } while (0)
#define STAGE_B(h, kt, b)                                                    \
  do {                                                                       \
    _Pragma("unroll") for (int j = 0; j < 2; ++j)                            \
        gload_lds16(B + (size_t)(n0 + (h)*128 + j * 64 + wid * 8 + srow) *   \
                            ldb + (kt)*64 + gcol,                            \
                    &lds[(b)*32768 + 16384 + (h)*8192 + j * 4096 +           \
                         wid * 512]);                                        \
  } while (0)
// read 4 m-frags x 2 ks from A buffer b at sub-row offset
#define RD_A(dst, b, sub)                                                    \
  do {                                                                       \
    _Pragma("unroll") for (int mi = 0; mi < 4; ++mi)                         \
        _Pragma("unroll") for (int ks = 0; ks < 2; ++ks)                     \
            dst[mi][ks] = *(const s16x8*)&lds[(b)*32768 +                    \
                (wm * 128 + (sub) + mi * 16 + rA) * 64 +                     \
                ((ks * 32 + kq) ^ xr)];                                      \
  } while (0)
#define RD_B(dst, b, sub)                                                    \
  do {                                                                       \
    _Pragma("unroll") for (int ni = 0; ni < 2; ++ni)                         \
        _Pragma("unroll") for (int ks = 0; ks < 2; ++ks)                     \
            dst[ni][ks] = *(const s16x8*)&lds[(b)*32768 + 16384 +            \
                (wn * 64 + (sub) + ni * 16 + rA) * 64 +                      \
                ((ks * 32 + kq) ^ xr)];                                      \
  } while (0)
#define MM(AF, BF, MO, NO)                                                   \
  do {                                                                       \
    _Pragma("unroll") for (int mi = 0; mi < 4; ++mi)                         \
        _Pragma("unroll") for (int ni = 0; ni < 2; ++ni)                     \
            _Pragma("unroll") for (int ks = 0; ks < 2; ++ks)                 \
                acc[(MO) + mi][(NO) + ni] =                                  \
                    __builtin_amdgcn_mfma_f32_16x16x32_bf16(                 \
                        AF[mi][ks], BF[ni][ks], acc[(MO) + mi][(NO) + ni],   \
                        0, 0, 0);                                            \
  } while (0)

  f32x4 acc[8][4] = {};
  const int NT = K >> 6;

  // prologue: K0 fully, K1 A-halves; keep 2 half-tiles in flight
  STAGE_A(0, 0, 0);
  STAGE_A(1, 0, 0);
  STAGE_B(0, 0, 0);
  STAGE_B(1, 0, 0);
  if (NT > 1) {
    STAGE_A(0, 1, 1);
    STAGE_A(1, 1, 1);
    WAITVM4();
  } else {
    WAITVM0();
  }
  BARRIER();

  s16x8 af0[4][2], af1[4][2], bf0[2][2], bf1[2][2];
  for (int t = 0; t < NT; ++t) {
    const int b = t & 1;
    // phase 1: (m-low x n-low)
    RD_A(af0, b, 0);
    RD_B(bf0, b, 0);
    if (t + 1 < NT) STAGE_B(0, t + 1, b ^ 1);
    BARRIER();
    WAITLGKM0();
    __builtin_amdgcn_s_setprio(1);
    MM(af0, bf0, 0, 0);
    __builtin_amdgcn_s_setprio(0);
    BARRIER();
    // phase 2: (m-high x n-low)
    RD_A(af1, b, 64);
    if (t + 1 < NT) STAGE_B(1, t + 1, b ^ 1);
    BARRIER();
    WAITLGKM0();
    __builtin_amdgcn_s_setprio(1);
    MM(af1, bf0, 4, 0);
    __builtin_amdgcn_s_setprio(0);
    BARRIER();
    // phase 3: (m-low x n-high); A-half reads of this buf completed ph2
    RD_B(bf1, b, 32);
    if (t + 2 < NT) STAGE_A(0, t + 2, b);
    BARRIER();
    WAITLGKM0();
    __builtin_amdgcn_s_setprio(1);
    MM(af0, bf1, 0, 2);
    __builtin_amdgcn_s_setprio(0);
    BARRIER();
    // phase 4: (m-high x n-high)
    if (t + 2 < NT) STAGE_A(1, t + 2, b);
    BARRIER();
    WAITLGKM0();
    __builtin_amdgcn_s_setprio(1);
    MM(af1, bf1, 4, 2);
    __builtin_amdgcn_s_setprio(0);
    // counted vmcnt: K(t+1) halves landed; K(t+2) A-halves stay in flight
    if (t + 2 < NT) {
      WAITVM4();
    } else {
      WAITVM0();
    }
    BARRIER();
  }

  // epilogue: row = m0+wm*128+mi*16+(lane>>4)*4+rr, col = n0+wn*64+nj*16+(lane&15)
  const int r4 = (lane >> 4) * 4;
#pragma unroll
  for (int nj = 0; nj < 4; ++nj) {
    const int col = n0 + wn * 64 + nj * 16 + (lane & 15);
    float bcol = 0.0f;
    if (MODE == 0) bcol = bias[col];
#pragma unroll
    for (int mi = 0; mi < 8; ++mi) {
#pragma unroll
      for (int rr = 0; rr < 4; ++rr) {
        const int row = m0 + wm * 128 + mi * 16 + r4 + rr;
        float v = acc[mi][nj][rr];
        if (MODE == 0) v += bcol;
        if (MODE == 1) v += bias[row];
        if (MODE == 0 || MODE == 1) {
          ((u16*)C)[(size_t)row * ldc + col] = f2b(v);
        } else if (MODE == 2) {
          ((u16*)C)[(size_t)row * ldc + col] = f2b(v * scale);
        } else {
          ((float*)C)[(size_t)row * ldc + col] = v;
        }
      }
    }
  }
#undef STAGE_A
#undef STAGE_B
#undef RD_A
#undef RD_B
#undef MM
}

// ------------- in-place row softmax on bf16 [nrows][4096] -------------
__global__ __launch_bounds__(256) void k_softmax(u16* __restrict__ S) {
  __shared__ float redm[4], reds[4];
  const int tid = threadIdx.x;
  const int lane = tid & 63;
  const int wid = tid >> 6;
  u16* sr = S + (size_t)blockIdx.x * 4096;
  s16x8 v[2];
#pragma unroll
  for (int i = 0; i < 2; ++i) v[i] = ((const s16x8*)sr)[i * 256 + tid];
  float f[16];
#pragma unroll
  for (int i = 0; i < 2; ++i)
#pragma unroll
    for (int j = 0; j < 8; ++j) f[i * 8 + j] = b2f((u16)v[i][j]);
  float m = -3.0e38f;
#pragma unroll
  for (int i = 0; i < 16; ++i) m = fmaxf(m, f[i]);
#pragma unroll
  for (int o = 32; o > 0; o >>= 1) m = fmaxf(m, __shfl_xor(m, o, 64));
  if (lane == 0) redm[wid] = m;
  __syncthreads();
  m = fmaxf(fmaxf(redm[0], redm[1]), fmaxf(redm[2], redm[3]));
  float s = 0.f;
#pragma unroll
  for (int i = 0; i < 16; ++i) {
    f[i] = __expf(f[i] - m);
    s += f[i];
  }
#pragma unroll
  for (int o = 32; o > 0; o >>= 1) s += __shfl_xor(s, o, 64);
  if (lane == 0) reds[wid] = s;
  __syncthreads();
  s = reds[0] + reds[1] + reds[2] + reds[3];
  const float inv = 1.0f / s;
#pragma unroll
  for (int i = 0; i < 2; ++i) {
    s16x8 h;
#pragma unroll
    for (int j = 0; j < 8; ++j) h[j] = (short)f2b(f[i * 8 + j] * inv);
    ((s16x8*)sr)[i * 256 + tid] = h;
  }
}

extern "C" void kernel_launch(void* const* d_in, const int* in_sizes, int n_in,
                              void* d_out, int out_size, void* d_ws,
                              size_t ws_size, hipStream_t stream) {
  const float* x = (const float*)d_in[0];
  const float* Wq = (const float*)d_in[1];
  const float* bq = (const float*)d_in[2];
  const float* Wk = (const float*)d_in[3];
  const float* bk = (const float*)d_in[4];
  const float* Wv = (const float*)d_in[5];
  const float* bv = (const float*)d_in[6];
  float* out = (float*)d_out;
  char* ws = (char*)d_ws;

  const size_t MB = 1ull << 20;
  u16* Qb = (u16*)(ws + 0 * MB);      // [4][4096][1024] bf16
  u16* Kb = (u16*)(ws + 32 * MB);     // [4][4096][1024] bf16
  u16* VtAll = (u16*)(ws + 64 * MB);  // [1024][16384] bf16 (V^T all batches)
  u16* Xb = (u16*)(ws + 96 * MB);     // [16384][1024] bf16, dead after proj
  u16* Sc = (u16*)(ws + 96 * MB);     // [4][4096][4096] bf16, reuses Xb
  u16* Wqb = (u16*)(ws + 224 * MB);
  u16* Wkb = Wqb + 1048576;
  u16* Wvb = Wqb + 2097152;

  // allow 128 KiB dynamic LDS (defensive; capture-safe, not a stream op)
  static bool attr_set = false;
  if (!attr_set) {
    hipFuncSetAttribute((const void*)k_gemm256<0>,
                        hipFuncAttributeMaxDynamicSharedMemorySize, 131072);
    hipFuncSetAttribute((const void*)k_gemm256<1>,
                        hipFuncAttributeMaxDynamicSharedMemorySize, 131072);
    hipFuncSetAttribute((const void*)k_gemm256<2>,
                        hipFuncAttributeMaxDynamicSharedMemorySize, 131072);
    hipFuncSetAttribute((const void*)k_gemm256<3>,
                        hipFuncAttributeMaxDynamicSharedMemorySize, 131072);
    attr_set = true;
  }

  // converts (x: 16,777,216 floats = 4,194,304 float4)
  k_cvt<<<16384, 256, 0, stream>>>(x, Xb, 4194304);
  k_cvt<<<1024, 256, 0, stream>>>(Wq, Wqb, 262144);
  k_cvt<<<1024, 256, 0, stream>>>(Wk, Wkb, 262144);
  k_cvt<<<1024, 256, 0, stream>>>(Wv, Wvb, 262144);

  dim3 blk(512);
  const size_t LDSB = 131072;
  // Q,K projections: M=16384, N=1024, K=1024 -> grid (4, 64)
  k_gemm256<0><<<dim3(4, 64, 1), blk, LDSB, stream>>>(
      Xb, Wqb, 1024, 1024, 1024, bq, Qb, 1024, 1.f, 0, 0, 0);
  k_gemm256<0><<<dim3(4, 64, 1), blk, LDSB, stream>>>(
      Xb, Wkb, 1024, 1024, 1024, bk, Kb, 1024, 1.f, 0, 0, 0);
  // V^T projection: C[d][s] = Wv@X^T + bv[d]; M=1024, N=16384 -> grid (64, 4)
  k_gemm256<1><<<dim3(64, 4, 1), blk, LDSB, stream>>>(
      Wvb, Xb, 1024, 1024, 1024, bv, VtAll, 16384, 1.f, 0, 0, 0);
  // scores (all batches): M=N=4096, K=1024 -> grid (16, 16, 4), bf16 * 1/32
  k_gemm256<2><<<dim3(16, 16, 4), blk, LDSB, stream>>>(
      Qb, Kb, 1024, 1024, 1024, nullptr, Sc, 4096, 0.03125f, 4194304, 4194304,
      (size_t)4096 * 4096 * 2);
  // softmax in place over all 16384 rows
  k_softmax<<<16384, 256, 0, stream>>>(Sc);
  // PV (all batches): M=4096, N=1024, K=4096 -> grid (4, 16, 4)
  k_gemm256<3><<<dim3(4, 16, 4), blk, LDSB, stream>>>(
      Sc, VtAll, 4096, 16384, 4096, nullptr, out, 1024, 1.f, 16777216, 4096,
      (size_t)4096 * 1024 * 4);
}